// Round 6
// baseline (334.294 us; speedup 1.0000x reference)
//
#include <hip/hip_runtime.h>

typedef float v4 __attribute__((ext_vector_type(4)));

__device__ __forceinline__ float leaky(float x) { return x >= 0.f ? x : 0.2f * x; }
__device__ __forceinline__ float elu(float x) { return x > 0.f ? x : expm1f(x); }

// ---- GEMM1 tile worker: h1[n,256] = emb[nidx[n],128] @ W1[128,256] + alpha epilogue ----
// tile = (node-tile of 64) * 4 + head; block 256 thr; thread tile 4n x 4c.
__device__ __forceinline__ void gemm1_tile(
    int tile, const int* __restrict__ nidx, const float* __restrict__ emb,
    const float* __restrict__ W1, const float* __restrict__ asv,
    const float* __restrict__ adv, float* __restrict__ h1,
    float* __restrict__ as1, float* __restrict__ ad1, int nN, float* smem) {
  float* xs = smem;             // 64*68
  float* Ws = smem + 64 * 68;   // 64*64
  int t = threadIdx.x;
  int nbase = (tile >> 2) * 64;
  int head  = tile & 3;
  int cbase = head * 64;
  int c0 = (t & 15) * 4;
  int n0 = (t >> 4) * 4;
  float acc[4][4];
  for (int i = 0; i < 4; ++i) for (int j = 0; j < 4; ++j) acc[i][j] = 0.f;
  v4 z = (v4)(0.f);
  for (int kc = 0; kc < 2; ++kc) {
    __syncthreads();
    {  // stage x: thread -> node t>>2, 16 k-floats
      int sn = t >> 2;
      int node = nbase + sn;
      int kp = (t & 3) * 16;
      bool v = node < nN;
      const float* sp = &emb[(size_t)nidx[v ? node : nN - 1] * 128 + kc * 64 + kp];
      v4 a0 = v ? *(const v4*)(sp + 0)  : z;
      v4 a1 = v ? *(const v4*)(sp + 4)  : z;
      v4 a2 = v ? *(const v4*)(sp + 8)  : z;
      v4 a3 = v ? *(const v4*)(sp + 12) : z;
      *(v4*)&xs[sn * 68 + kp + 0]  = a0;
      *(v4*)&xs[sn * 68 + kp + 4]  = a1;
      *(v4*)&xs[sn * 68 + kp + 8]  = a2;
      *(v4*)&xs[sn * 68 + kp + 12] = a3;
    }
    {  // stage W: thread -> k-row t>>2, 16 c-floats
      int kk = t >> 2;
      int cp = (t & 3) * 16;
      const float* wp = &W1[(size_t)(kc * 64 + kk) * 256 + cbase + cp];
      v4 w0 = *(const v4*)(wp + 0);
      v4 w1 = *(const v4*)(wp + 4);
      v4 w2 = *(const v4*)(wp + 8);
      v4 w3 = *(const v4*)(wp + 12);
      *(v4*)&Ws[kk * 64 + cp + 0]  = w0;
      *(v4*)&Ws[kk * 64 + cp + 4]  = w1;
      *(v4*)&Ws[kk * 64 + cp + 8]  = w2;
      *(v4*)&Ws[kk * 64 + cp + 12] = w3;
    }
    __syncthreads();
    #pragma unroll 4
    for (int kk = 0; kk < 64; kk += 4) {
      v4 xv[4], wv[4];
      for (int i = 0; i < 4; ++i) xv[i] = *(const v4*)&xs[(n0 + i) * 68 + kk];
      for (int j = 0; j < 4; ++j) wv[j] = *(const v4*)&Ws[(kk + j) * 64 + c0];
      for (int i = 0; i < 4; ++i)
        for (int j = 0; j < 4; ++j) {
          float xd = xv[i][j];
          acc[i][0] += xd * wv[j][0];
          acc[i][1] += xd * wv[j][1];
          acc[i][2] += xd * wv[j][2];
          acc[i][3] += xd * wv[j][3];
        }
    }
  }
  v4 asl = *(const v4*)&asv[cbase + c0];
  v4 adl = *(const v4*)&adv[cbase + c0];
  for (int i = 0; i < 4; ++i) {
    int node = nbase + n0 + i;
    v4 o; o[0] = acc[i][0]; o[1] = acc[i][1]; o[2] = acc[i][2]; o[3] = acc[i][3];
    float ps = o[0]*asl[0] + o[1]*asl[1] + o[2]*asl[2] + o[3]*asl[3];
    float pd = o[0]*adl[0] + o[1]*adl[1] + o[2]*adl[2] + o[3]*adl[3];
    ps += __shfl_xor(ps, 1); pd += __shfl_xor(pd, 1);
    ps += __shfl_xor(ps, 2); pd += __shfl_xor(pd, 2);
    ps += __shfl_xor(ps, 4); pd += __shfl_xor(pd, 4);
    ps += __shfl_xor(ps, 8); pd += __shfl_xor(pd, 8);
    if (node < nN) {
      *(v4*)&h1[(size_t)node * 256 + cbase + c0] = o;
      if ((t & 15) == 0) {
        as1[(size_t)node * 4 + head] = ps;
        ad1[(size_t)node * 4 + head] = pd;
      }
    }
  }
}

// ---- D2: gemm1 tiles [0,g1) + edge degree count; last deg block runs the scan ----
__global__ __launch_bounds__(256) void k_d2(
    const int* __restrict__ nidx, const float* __restrict__ emb,
    const float* __restrict__ W1, const float* __restrict__ asv,
    const float* __restrict__ adv, float* __restrict__ h1,
    float* __restrict__ as1, float* __restrict__ ad1,
    const int* __restrict__ ei, int* __restrict__ deg,
    int* __restrict__ rowptr, int* __restrict__ cursor, int* __restrict__ ctr2,
    int nN, int nE, int eT, int g1, int ndeg) {
  __shared__ __align__(16) float smem[64 * 68 + 64 * 64];
  __shared__ int lastflag;
  int b = blockIdx.x;
  int t = threadIdx.x;
  if (b < g1) { gemm1_tile(b, nidx, emb, W1, asv, adv, h1, as1, ad1, nN, smem); return; }
  int bid = b - g1;
  for (int r = 0; r < 4; ++r) {
    int e = bid * 1024 + r * 256 + t;
    if (e < eT) {
      int d = (e < nE) ? ei[nE + e] : (e - nE);   // self-loops appended after real edges
      atomicAdd(&deg[d], 1);
    }
  }
  __syncthreads();                 // drains this block's atomics (vmcnt 0 before barrier)
  if (t == 0) {
    __threadfence();
    int old = atomicAdd(ctr2, 1);
    lastflag = (old == ndeg - 1);
  }
  __syncthreads();
  if (!lastflag) return;
  // --- exclusive scan of deg -> rowptr/cursor, by this single block (256 thr) ---
  int* sd = (int*)smem;
  int chunk = (nN + 255) >> 8;
  int beg = t * chunk;
  int end = beg + chunk; if (end > nN) end = nN;
  int s = 0;
  for (int i = beg; i < end; ++i) s += atomicAdd(&deg[i], 0);  // coherent read
  sd[t] = s;
  __syncthreads();
  for (int off = 1; off < 256; off <<= 1) {
    int v = (t >= off) ? sd[t - off] : 0;
    __syncthreads();
    sd[t] += v;
    __syncthreads();
  }
  int run = sd[t] - s;
  for (int i = beg; i < end; ++i) {
    int dv = atomicAdd(&deg[i], 0);
    rowptr[i] = run; cursor[i] = run; run += dv;
  }
  if (t == 0) rowptr[nN] = eT;
}

// ---- D3: gemm1 tiles [g1,2*g1) + edge scatter into dst-sorted srt ----
__global__ __launch_bounds__(256) void k_d3(
    const int* __restrict__ nidx, const float* __restrict__ emb,
    const float* __restrict__ W1, const float* __restrict__ asv,
    const float* __restrict__ adv, float* __restrict__ h1,
    float* __restrict__ as1, float* __restrict__ ad1,
    const int* __restrict__ ei, int* __restrict__ cursor, int* __restrict__ srt,
    int nN, int nE, int eT, int g1) {
  __shared__ __align__(16) float smem[64 * 68 + 64 * 64];
  int b = blockIdx.x;
  int t = threadIdx.x;
  if (b < g1) { gemm1_tile(g1 + b, nidx, emb, W1, asv, adv, h1, as1, ad1, nN, smem); return; }
  int bid = b - g1;
  for (int r = 0; r < 4; ++r) {
    int e = bid * 1024 + r * 256 + t;
    if (e < eT) {
      int s, d;
      if (e < nE) { s = ei[e]; d = ei[nE + e]; } else { s = d = e - nE; }
      int pos = atomicAdd(&cursor[d], 1);
      srt[pos] = s;
    }
  }
}

// ---- layer-1 softmax + aggregate + bias + ELU: one wave per node, barrier-free ----
__global__ __launch_bounds__(256) void k_agg1(
    const float* __restrict__ h1, const float* __restrict__ as1,
    const float* __restrict__ ad1, const float* __restrict__ b1,
    const int* __restrict__ rowptr, const int* __restrict__ srt,
    float* __restrict__ x2, int nN) {
  __shared__ int   ss[4][64];
  __shared__ float sw[4][256];
  int t = threadIdx.x;
  int wv = t >> 6, lane = t & 63;
  int n = blockIdx.x * 4 + wv;
  if (n >= nN) return;                     // whole wave exits; no block barriers
  int ms0 = rowptr[n], ms1 = rowptr[n + 1];
  v4 adn = *(const v4*)&ad1[(size_t)n * 4];
  int h = lane >> 4;
  v4 acc = (v4)(0.f);
  float den = 0.f;
  for (int base = ms0; base < ms1; base += 64) {
    int m = ms1 - base; if (m > 64) m = 64;
    asm volatile("s_waitcnt lgkmcnt(0)" ::: "memory");
    __builtin_amdgcn_wave_barrier();
    if (lane < m) {
      int s = srt[base + lane];
      ss[wv][lane] = s;
      v4 a = *(const v4*)&as1[(size_t)s * 4];
      sw[wv][lane * 4 + 0] = __expf(leaky(a[0] + adn[0]));
      sw[wv][lane * 4 + 1] = __expf(leaky(a[1] + adn[1]));
      sw[wv][lane * 4 + 2] = __expf(leaky(a[2] + adn[2]));
      sw[wv][lane * 4 + 3] = __expf(leaky(a[3] + adn[3]));
    }
    asm volatile("s_waitcnt lgkmcnt(0)" ::: "memory");
    __builtin_amdgcn_wave_barrier();
    #pragma unroll 8
    for (int j = 0; j < m; ++j) {
      int s = ss[wv][j];
      float wj = sw[wv][j * 4 + h];
      v4 hv = *(const v4*)&h1[(size_t)s * 256 + lane * 4];
      acc[0] += wj * hv[0];
      acc[1] += wj * hv[1];
      acc[2] += wj * hv[2];
      acc[3] += wj * hv[3];
      den += wj;
    }
  }
  v4 bb = *(const v4*)&b1[lane * 4];
  float inv = 1.f / den;
  v4 o;
  o[0] = elu(acc[0] * inv + bb[0]);
  o[1] = elu(acc[1] * inv + bb[1]);
  o[2] = elu(acc[2] * inv + bb[2]);
  o[3] = elu(acc[3] * inv + bb[3]);
  *(v4*)&x2[(size_t)n * 256 + lane * 4] = o;
}

// ---- GEMM2: h2[n,64] = x2[n,256] @ W2[256,64]; epilogue computes as2/ad2 ----
__global__ __launch_bounds__(256) void k_gemm2(
    const float* __restrict__ x2, const float* __restrict__ W2,
    const float* __restrict__ asv, const float* __restrict__ adv,
    float* __restrict__ h2, float* __restrict__ as2, float* __restrict__ ad2, int nN) {
  __shared__ __align__(16) float xs[32 * 68];  // [n][k], stride 68
  __shared__ __align__(16) float Ws[64 * 64];  // [k][c] row-major
  int t = threadIdx.x;
  int nbase = blockIdx.x * 32;
  int c0 = (t & 15) * 4;
  int n0 = (t >> 4) * 2;
  float acc[2][4];
  for (int i = 0; i < 2; ++i) for (int j = 0; j < 4; ++j) acc[i][j] = 0.f;
  v4 z = (v4)(0.f);
  for (int kc = 0; kc < 4; ++kc) {
    __syncthreads();
    {  // stage x: thread -> node t>>3, 8 k-floats
      int sn = t >> 3;
      int node = nbase + sn;
      int kp = (t & 7) * 8;
      bool v = node < nN;
      const float* sp = &x2[(size_t)(v ? node : nN - 1) * 256 + kc * 64 + kp];
      v4 a0 = v ? *(const v4*)(sp + 0) : z;
      v4 a1 = v ? *(const v4*)(sp + 4) : z;
      *(v4*)&xs[sn * 68 + kp + 0] = a0;
      *(v4*)&xs[sn * 68 + kp + 4] = a1;
    }
    {  // stage W: thread -> k-row t>>2, 16 c-floats
      int kk = t >> 2;
      int cp = (t & 3) * 16;
      const float* wp = &W2[(size_t)(kc * 64 + kk) * 64 + cp];
      v4 w0 = *(const v4*)(wp + 0);
      v4 w1 = *(const v4*)(wp + 4);
      v4 w2 = *(const v4*)(wp + 8);
      v4 w3 = *(const v4*)(wp + 12);
      *(v4*)&Ws[kk * 64 + cp + 0]  = w0;
      *(v4*)&Ws[kk * 64 + cp + 4]  = w1;
      *(v4*)&Ws[kk * 64 + cp + 8]  = w2;
      *(v4*)&Ws[kk * 64 + cp + 12] = w3;
    }
    __syncthreads();
    #pragma unroll 4
    for (int kk = 0; kk < 64; kk += 4) {
      v4 xv[2], wv[4];
      for (int i = 0; i < 2; ++i) xv[i] = *(const v4*)&xs[(n0 + i) * 68 + kk];
      for (int j = 0; j < 4; ++j) wv[j] = *(const v4*)&Ws[(kk + j) * 64 + c0];
      for (int i = 0; i < 2; ++i)
        for (int j = 0; j < 4; ++j) {
          float xd = xv[i][j];
          acc[i][0] += xd * wv[j][0];
          acc[i][1] += xd * wv[j][1];
          acc[i][2] += xd * wv[j][2];
          acc[i][3] += xd * wv[j][3];
        }
    }
  }
  v4 asl = *(const v4*)&asv[c0];
  v4 adl = *(const v4*)&adv[c0];
  for (int i = 0; i < 2; ++i) {
    int node = nbase + n0 + i;
    v4 o; o[0] = acc[i][0]; o[1] = acc[i][1]; o[2] = acc[i][2]; o[3] = acc[i][3];
    float ps = o[0]*asl[0] + o[1]*asl[1] + o[2]*asl[2] + o[3]*asl[3];
    float pd = o[0]*adl[0] + o[1]*adl[1] + o[2]*adl[2] + o[3]*adl[3];
    ps += __shfl_xor(ps, 1); pd += __shfl_xor(pd, 1);
    ps += __shfl_xor(ps, 2); pd += __shfl_xor(pd, 2);
    ps += __shfl_xor(ps, 4); pd += __shfl_xor(pd, 4);
    ps += __shfl_xor(ps, 8); pd += __shfl_xor(pd, 8);
    if (node < nN) {
      *(v4*)&h2[(size_t)node * 64 + c0] = o;
      if ((t & 15) == 0) { as2[node] = ps; ad2[node] = pd; }
    }
  }
}

// ---- TAIL: fused layer-2 aggregate + ELU + gate MLP + softmax pool + final ----
// grid fixed 256 blocks x 256 thr (1024 waves); wave processes nodes strided by 1024.
__global__ __launch_bounds__(256) void k_tail(
    const float* __restrict__ h2, const float* __restrict__ as2,
    const float* __restrict__ ad2, const float* __restrict__ b2,
    const int* __restrict__ rowptr, const int* __restrict__ srt,
    const float* __restrict__ gW1, const float* __restrict__ gb1,
    const float* __restrict__ gW2, const float* __restrict__ gb2,
    float* __restrict__ pnum, float* __restrict__ pden, int* __restrict__ ctr3,
    float* __restrict__ out, int nN) {
  __shared__ __align__(16) float gwT[64 * 68];   // gW1^T padded
  __shared__ int   ss[4][64];
  __shared__ float sw[4][64];
  __shared__ float xr[4][64];
  __shared__ float snum[4][64];
  __shared__ float sden[4];
  __shared__ int lastflag;
  int t = threadIdx.x;
  int wv = t >> 6, lane = t & 63;
  for (int i = t; i < 4096; i += 256) {
    int d = i >> 6, c = i & 63;
    gwT[c * 68 + d] = gW1[i];
  }
  float gb1l = gb1[lane], gw2l = gW2[lane], gb2s = gb2[0], b2l = b2[lane];
  __syncthreads();
  float num = 0.f, denp = 0.f;
  for (int n = blockIdx.x * 4 + wv; n < nN; n += 1024) {
    int ms0 = rowptr[n], ms1 = rowptr[n + 1];
    float adn = ad2[n];
    float acc = 0.f, den = 0.f;
    for (int base = ms0; base < ms1; base += 64) {
      int m = ms1 - base; if (m > 64) m = 64;
      asm volatile("s_waitcnt lgkmcnt(0)" ::: "memory");
      __builtin_amdgcn_wave_barrier();
      if (lane < m) {
        int s = srt[base + lane];
        ss[wv][lane] = s;
        sw[wv][lane] = __expf(leaky(as2[s] + adn));
      }
      asm volatile("s_waitcnt lgkmcnt(0)" ::: "memory");
      __builtin_amdgcn_wave_barrier();
      #pragma unroll 8
      for (int j = 0; j < m; ++j) {
        int s = ss[wv][j];
        float wj = sw[wv][j];
        acc += wj * h2[(size_t)s * 64 + lane];
        den += wj;
      }
    }
    float x3v = elu(acc / den + b2l);
    // gate MLP on this node's 64-vector (wave-private LDS round-trip)
    asm volatile("s_waitcnt lgkmcnt(0)" ::: "memory");
    __builtin_amdgcn_wave_barrier();
    xr[wv][lane] = x3v;
    asm volatile("s_waitcnt lgkmcnt(0)" ::: "memory");
    __builtin_amdgcn_wave_barrier();
    float hid = gb1l;
    for (int d4 = 0; d4 < 64; d4 += 4) {
      v4 xs4 = *(const v4*)&xr[wv][d4];
      v4 gv  = *(const v4*)&gwT[lane * 68 + d4];
      hid += xs4[0] * gv[0] + xs4[1] * gv[1] + xs4[2] * gv[2] + xs4[3] * gv[3];
    }
    hid = fmaxf(hid, 0.f);
    float p = hid * gw2l;
    for (int o = 32; o; o >>= 1) p += __shfl_xor(p, o);
    float g = __expf(p + gb2s);
    num += g * x3v;
    denp += g;
  }
  snum[wv][lane] = num;
  if (lane == 0) sden[wv] = denp;
  __syncthreads();
  if (t < 64) atomicAdd(&pnum[t], snum[0][t] + snum[1][t] + snum[2][t] + snum[3][t]);
  if (t == 0) atomicAdd(pden, sden[0] + sden[1] + sden[2] + sden[3]);
  __syncthreads();                 // drains the atomics of all threads in this block
  if (t == 0) {
    __threadfence();
    int old = atomicAdd(ctr3, 1);
    lastflag = (old == (int)gridDim.x - 1);
  }
  __syncthreads();
  if (lastflag && t < 64) {
    float nv = atomicAdd(&pnum[t], 0.f);   // coherent read
    float dv = atomicAdd(pden, 0.f);
    out[t] = nv / dv;
  }
}

extern "C" void kernel_launch(void* const* d_in, const int* in_sizes, int n_in,
                              void* d_out, int out_size, void* d_ws, size_t ws_size,
                              hipStream_t stream) {
  const int*   nidx = (const int*)d_in[0];
  const int*   ei   = (const int*)d_in[1];
  const float* emb  = (const float*)d_in[2];
  const float* W1   = (const float*)d_in[3];
  const float* as1v = (const float*)d_in[4];
  const float* ad1v = (const float*)d_in[5];
  const float* b1   = (const float*)d_in[6];
  const float* W2   = (const float*)d_in[7];
  const float* as2v = (const float*)d_in[8];
  const float* ad2v = (const float*)d_in[9];
  const float* b2   = (const float*)d_in[10];
  const float* gW1  = (const float*)d_in[11];
  const float* gb1  = (const float*)d_in[12];
  const float* gW2  = (const float*)d_in[13];
  const float* gb2  = (const float*)d_in[14];
  float* out = (float*)d_out;

  const int nN = in_sizes[0];
  const int nE = in_sizes[1] / 2;
  const int eT = nE + nN;

  float* f = (float*)d_ws;
  size_t off = 0;
  float* h1   = f + off; off += (size_t)nN * 256;   // reused as h2 after agg1
  float* x2   = f + off; off += (size_t)nN * 256;
  float* as1  = f + off; off += (size_t)nN * 4;
  float* ad1  = f + off; off += (size_t)nN * 4;
  float* as2  = f + off; off += nN;
  float* ad2  = f + off; off += nN;
  int* rowptr = (int*)(f + off); off += nN + 1;
  int* cursor = (int*)(f + off); off += nN;
  int* srt    = (int*)(f + off); off += eT;
  // contiguous zeroed region: deg, pnum, pden, ctr2, ctr3
  int*   deg  = (int*)(f + off); off += nN;
  float* pnum = f + off; off += 64;
  float* pden = f + off; off += 1;
  int*   ctr2 = (int*)(f + off); off += 1;
  int*   ctr3 = (int*)(f + off); off += 1;

  float* h2 = h1;

  hipMemsetAsync(deg, 0, (size_t)(nN + 67) * sizeof(int), stream);

  int nt64 = (nN + 63) / 64;          // node tiles of 64
  int g1   = (nt64 * 4 + 1) / 2;      // half the gemm1 tiles per fused dispatch
  int g1b  = nt64 * 4 - g1;
  int ndeg = (eT + 1023) / 1024;      // edge blocks (256 thr x 4 edges)

  k_d2<<<g1 + ndeg, 256, 0, stream>>>(nidx, emb, W1, as1v, ad1v, h1, as1, ad1,
                                      ei, deg, rowptr, cursor, ctr2,
                                      nN, nE, eT, g1, ndeg);
  k_d3<<<g1b + ndeg, 256, 0, stream>>>(nidx, emb, W1, as1v, ad1v, h1, as1, ad1,
                                       ei, cursor, srt, nN, nE, eT, g1);

  k_agg1 <<<(nN + 3) / 4, 256, 0, stream>>>(h1, as1, ad1, b1, rowptr, srt, x2, nN);
  k_gemm2<<<(nN + 31) / 32, 256, 0, stream>>>(x2, W2, as2v, ad2v, h2, as2, ad2, nN);
  k_tail <<<256, 256, 0, stream>>>(h2, as2, ad2, b2, rowptr, srt,
                                   gW1, gb1, gW2, gb2, pnum, pden, ctr3, out, nN);
}